// Round 2
// baseline (1716.099 us; speedup 1.0000x reference)
//
#include <hip/hip_runtime.h>
#include <hip/hip_bf16.h>

typedef short short8_t __attribute__((ext_vector_type(8)));
typedef float float4_t __attribute__((ext_vector_type(4)));

#define MFMA16(A, B, C) __builtin_amdgcn_mfma_f32_16x16x32_bf16((A), (B), (C), 0, 0, 0)

#define SEQ 2048
#define HD 128
#define NH 32
#define NKV 8

__device__ inline short f2bs(float f) {
    union { __hip_bfloat16 h; short s; } u;
    u.h = __float2bfloat16(f);
    return u.s;
}

// load 8 contiguous elements as bf16 bit-pattern vector
__device__ inline short8_t load8(const __hip_bfloat16* p) {
    return *(const short8_t*)p;
}
__device__ inline short8_t load8(const float* p) {
    float4_t a = *(const float4_t*)p;
    float4_t b = *(const float4_t*)(p + 4);
    short8_t r;
    r[0] = f2bs(a[0]); r[1] = f2bs(a[1]); r[2] = f2bs(a[2]); r[3] = f2bs(a[3]);
    r[4] = f2bs(b[0]); r[5] = f2bs(b[1]); r[6] = f2bs(b[2]); r[7] = f2bs(b[3]);
    return r;
}

__device__ inline void store_c(__hip_bfloat16* p, float v) { *p = __float2bfloat16(v); }
__device__ inline void store_c(float* p, float v)          { *p = v; }

// ---------------------------------------------------------------------------
// C[m][n] = sum_k A[m][k] * B[n][k]   (row-major, K-contiguous; "NT")
// M, N multiples of 128; K multiple of 32. 256 threads = 4 waves.
// Tile 128x128, BK=32. Each wave computes a 64x64 quadrant (4x4 MFMA tiles).
// fp32 operands are converted to bf16 during LDS staging.
// ---------------------------------------------------------------------------
template <typename TA, typename TB, typename TC>
__global__ __launch_bounds__(256) void gemm_bt(
    const TA* __restrict__ A,
    const TB* __restrict__ B,
    TC* __restrict__ C,
    int M, int N, int K)
{
    __shared__ short As[128][40];  // +8 pad: 2-way bank aliasing (free)
    __shared__ short Bs[128][40];

    const int tid  = threadIdx.x;
    const int wave = tid >> 6;
    const int lane = tid & 63;
    const int quad = lane >> 4;
    const int l16  = lane & 15;
    const int m0 = blockIdx.y * 128;
    const int n0 = blockIdx.x * 128;
    const int wm = (wave >> 1) * 64;
    const int wn = (wave & 1) * 64;

    const int srow = tid >> 2;        // 0..63
    const int sseg = (tid & 3) * 8;   // 0,8,16,24 (elems)

    float4_t acc[4][4] = {};          // [mt][nt]

    for (int k0 = 0; k0 < K; k0 += 32) {
        short8_t a1 = load8(A + (size_t)(m0 + srow)      * K + k0 + sseg);
        short8_t a2 = load8(A + (size_t)(m0 + srow + 64) * K + k0 + sseg);
        short8_t b1 = load8(B + (size_t)(n0 + srow)      * K + k0 + sseg);
        short8_t b2 = load8(B + (size_t)(n0 + srow + 64) * K + k0 + sseg);
        __syncthreads();              // prior-iter LDS reads done before overwrite
        *(short8_t*)&As[srow][sseg]      = a1;
        *(short8_t*)&As[srow + 64][sseg] = a2;
        *(short8_t*)&Bs[srow][sseg]      = b1;
        *(short8_t*)&Bs[srow + 64][sseg] = b2;
        __syncthreads();

        short8_t af[4], bf[4];
#pragma unroll
        for (int t = 0; t < 4; t++)
            af[t] = *(const short8_t*)&As[wm + t * 16 + l16][quad * 8];
#pragma unroll
        for (int t = 0; t < 4; t++)
            bf[t] = *(const short8_t*)&Bs[wn + t * 16 + l16][quad * 8];
#pragma unroll
        for (int mt = 0; mt < 4; mt++)
#pragma unroll
            for (int nt = 0; nt < 4; nt++)
                acc[mt][nt] = MFMA16(af[mt], bf[nt], acc[mt][nt]);
    }

#pragma unroll
    for (int mt = 0; mt < 4; mt++)
#pragma unroll
        for (int nt = 0; nt < 4; nt++)
#pragma unroll
            for (int r = 0; r < 4; r++) {
                int row = m0 + wm + mt * 16 + quad * 4 + r;   // m
                int col = n0 + wn + nt * 16 + l16;            // n
                store_c(&C[(size_t)row * N + col], acc[mt][nt][r]);
            }
}

// ---------------------------------------------------------------------------
// RoPE in-place on [rows][cols] bf16 where cols = nheads*128; one thread per
// (even,odd) pair. shift = log2(pairs per row). pos = row % SEQ.
// freqs are fp32 [SEQ][64].
// ---------------------------------------------------------------------------
__global__ __launch_bounds__(256) void rope_kernel(
    __hip_bfloat16* __restrict__ x,
    const float* __restrict__ cs,
    const float* __restrict__ sn,
    int npairs, int shift)
{
    int pi = blockIdx.x * 256 + threadIdx.x;
    if (pi >= npairs) return;
    int cols = 1 << shift;
    int cp   = pi & (cols - 1);     // pair index within row = h*64 + d
    int row  = pi >> shift;
    int d    = cp & 63;
    int pos  = row & (SEQ - 1);
    float c = cs[pos * 64 + d];
    float s = sn[pos * 64 + d];
    __hip_bfloat16* p = x + (((size_t)row) << (shift + 1)) + (size_t)cp * 2;
    float x0 = __bfloat162float(p[0]);
    float x1 = __bfloat162float(p[1]);
    p[0] = __float2bfloat16(x0 * c - x1 * s);
    p[1] = __float2bfloat16(x0 * s + x1 * c);
}

// ---------------------------------------------------------------------------
// Causal GQA flash attention. Grid: (S/64, NH, B). Block: 256 = 4 waves.
// Wave w owns Q-rows [w*16, w*16+16) of the 64-row Q tile, full HD=128.
// K-tiles of 64 keys; online softmax; P round-trips through LDS to become an
// MFMA A-operand; V staged transposed so PV B-frags are ds_read_b128.
// ---------------------------------------------------------------------------
__global__ __launch_bounds__(256) void flash_kernel(
    const __hip_bfloat16* __restrict__ Q,
    const __hip_bfloat16* __restrict__ Km,
    const __hip_bfloat16* __restrict__ Vm,
    __hip_bfloat16* __restrict__ O)
{
    __shared__ __hip_bfloat16 Qs[64][136];     // 136*2B = 272B = 17*16B rows
    __shared__ __hip_bfloat16 Ks[64][136];
    __shared__ __hip_bfloat16 Vt[128][72];     // V transposed: Vt[d][key]
    __shared__ __hip_bfloat16 Ps[4][16][72];   // per-wave P buffer

    const int tid  = threadIdx.x;
    const int wave = tid >> 6;
    const int lane = tid & 63;
    const int quad = lane >> 4;
    const int l16  = lane & 15;
    const int qt  = blockIdx.x;
    const int h   = blockIdx.y;
    const int b   = blockIdx.z;
    const int kvh = h >> 2;                    // GQA: 4 Q-heads per KV head
    const int q0  = qt * 64;
    const float scale = 0.08838834764831845f;  // 1/sqrt(128)

    // Load Q tile once: rows q0..q0+63, cols h*128..+127
    {
        const int seg = (tid & 15) * 8;
        const int row = tid >> 4;
#pragma unroll
        for (int i = 0; i < 4; i++) {
            int r = row + i * 16;
            uint4 v = *(const uint4*)(Q + (size_t)(b * SEQ + q0 + r) * (NH * HD) + h * HD + seg);
            *(uint4*)&Qs[r][seg] = v;
        }
    }

    float4_t acc_o[8] = {};
    float m_st[4], l_st[4];
#pragma unroll
    for (int r = 0; r < 4; r++) { m_st[r] = -1e30f; l_st[r] = 0.f; }

    for (int kt = 0; kt <= qt; kt++) {
        __syncthreads();  // prior-iter Ks/Vt reads done
        {
            const int seg = (tid & 15) * 8;
            const int row = tid >> 4;
#pragma unroll
            for (int i = 0; i < 4; i++) {
                int r = row + i * 16;
                size_t grow = (size_t)(b * SEQ + kt * 64 + r) * (NKV * HD) + kvh * HD + seg;
                uint4 kv = *(const uint4*)(Km + grow);
                *(uint4*)&Ks[r][seg] = kv;
                uint4 vv = *(const uint4*)(Vm + grow);
                const __hip_bfloat16* pv = (const __hip_bfloat16*)&vv;
#pragma unroll
                for (int j = 0; j < 8; j++)
                    Vt[seg + j][r] = pv[j];
            }
        }
        __syncthreads();

        // S = Q K^T for this wave's 16 rows x 64 keys
        float4_t sc[4] = {};
#pragma unroll
        for (int kk = 0; kk < 4; kk++) {
            short8_t aq = *(const short8_t*)&Qs[wave * 16 + l16][kk * 32 + quad * 8];
#pragma unroll
            for (int nt = 0; nt < 4; nt++) {
                short8_t bk = *(const short8_t*)&Ks[nt * 16 + l16][kk * 32 + quad * 8];
                sc[nt] = MFMA16(aq, bk, sc[nt]);
            }
        }

        // mask + scale + online softmax (row = quad*4 + r, col = nt*16 + l16)
        float pr[4][4];   // [nt][r]
        float alpha[4];
#pragma unroll
        for (int r = 0; r < 4; r++) {
            int qrow = q0 + wave * 16 + quad * 4 + r;
            float sv[4];
            float mx = -1e30f;
#pragma unroll
            for (int nt = 0; nt < 4; nt++) {
                int key = kt * 64 + nt * 16 + l16;
                float s = sc[nt][r] * scale;
                if (key > qrow) s = -1e30f;
                sv[nt] = s;
                mx = fmaxf(mx, s);
            }
#pragma unroll
            for (int off = 1; off < 16; off <<= 1)
                mx = fmaxf(mx, __shfl_xor(mx, off, 64));
            float mnew = fmaxf(m_st[r], mx);
            float al   = __expf(m_st[r] - mnew);
            float rsum = 0.f;
#pragma unroll
            for (int nt = 0; nt < 4; nt++) {
                float pv = __expf(sv[nt] - mnew);
                pr[nt][r] = pv;
                rsum += pv;
            }
#pragma unroll
            for (int off = 1; off < 16; off <<= 1)
                rsum += __shfl_xor(rsum, off, 64);
            l_st[r]  = l_st[r] * al + rsum;
            m_st[r]  = mnew;
            alpha[r] = al;
        }

        // rescale O, stash P to LDS for A-operand layout
#pragma unroll
        for (int nt2 = 0; nt2 < 8; nt2++)
#pragma unroll
            for (int r = 0; r < 4; r++)
                acc_o[nt2][r] *= alpha[r];
#pragma unroll
        for (int r = 0; r < 4; r++)
#pragma unroll
            for (int nt = 0; nt < 4; nt++)
                Ps[wave][quad * 4 + r][nt * 16 + l16] = __float2bfloat16(pr[nt][r]);
        __syncthreads();  // drain LDS writes (also keeps waves uniform)

        // O += P @ V  (A = P 16x64, B-frags from Vt[d][key])
#pragma unroll
        for (int kk = 0; kk < 2; kk++) {
            short8_t ap = *(const short8_t*)&Ps[wave][l16][kk * 32 + quad * 8];
#pragma unroll
            for (int nt2 = 0; nt2 < 8; nt2++) {
                short8_t bv = *(const short8_t*)&Vt[nt2 * 16 + l16][kk * 32 + quad * 8];
                acc_o[nt2] = MFMA16(ap, bv, acc_o[nt2]);
            }
        }
    }

    // epilogue: O / l
#pragma unroll
    for (int nt2 = 0; nt2 < 8; nt2++)
#pragma unroll
        for (int r = 0; r < 4; r++) {
            int qrow = q0 + wave * 16 + quad * 4 + r;
            int d    = nt2 * 16 + l16;
            float v  = acc_o[nt2][r] / l_st[r];
            O[(size_t)(b * SEQ + qrow) * (NH * HD) + h * HD + d] = __float2bfloat16(v);
        }
}

// ---------------------------------------------------------------------------
extern "C" void kernel_launch(void* const* d_in, const int* in_sizes, int n_in,
                              void* d_out, int out_size, void* d_ws, size_t ws_size,
                              hipStream_t stream)
{
    const float* x  = (const float*)d_in[0];
    const float* fc = (const float*)d_in[1];
    const float* fs = (const float*)d_in[2];
    const float* wq = (const float*)d_in[3];
    const float* wk = (const float*)d_in[4];
    const float* wv = (const float*)d_in[5];
    const float* wo = (const float*)d_in[6];
    float* out = (float*)d_out;

    const int BS = 2 * SEQ;  // 4096 rows
    char* ws = (char*)d_ws;
    __hip_bfloat16* q    = (__hip_bfloat16*)(ws);                         // 4096x4096 bf16
    __hip_bfloat16* k    = (__hip_bfloat16*)(ws + (size_t)33554432);      // 4096x1024 bf16
    __hip_bfloat16* v    = (__hip_bfloat16*)(ws + (size_t)41943040);      // 4096x1024 bf16
    __hip_bfloat16* attn = (__hip_bfloat16*)(ws + (size_t)50331648);      // 4096x4096 bf16

    // QKV projections (B^T GEMMs), fp32 inputs -> bf16 outputs
    gemm_bt<<<dim3(32, 32), 256, 0, stream>>>(x, wq, q, BS, NH * HD, 4096);
    gemm_bt<<<dim3(8, 32),  256, 0, stream>>>(x, wk, k, BS, NKV * HD, 4096);
    gemm_bt<<<dim3(8, 32),  256, 0, stream>>>(x, wv, v, BS, NKV * HD, 4096);

    // RoPE on q (32 heads) and k (8 heads)
    {
        int npq = BS * NH * 64;   // 2048 pairs/row -> shift 11
        rope_kernel<<<(npq + 255) / 256, 256, 0, stream>>>(q, fc, fs, npq, 11);
        int npk = BS * NKV * 64;  // 512 pairs/row -> shift 9
        rope_kernel<<<(npk + 255) / 256, 256, 0, stream>>>(k, fc, fs, npk, 9);
    }

    // causal GQA flash attention
    flash_kernel<<<dim3(SEQ / 64, NH, 2), 256, 0, stream>>>(q, k, v, attn);

    // output projection: bf16 attn x fp32 wo -> fp32 out
    gemm_bt<<<dim3(32, 32), 256, 0, stream>>>(attn, wo, out, BS, NH * HD, 4096);
}

// Round 3
// 1243.958 us; speedup vs baseline: 1.3795x; 1.3795x over previous
//
#include <hip/hip_runtime.h>
#include <hip/hip_bf16.h>

typedef short short8_t __attribute__((ext_vector_type(8)));
typedef float float4_t __attribute__((ext_vector_type(4)));

#define MFMA16(A, B, C) __builtin_amdgcn_mfma_f32_16x16x32_bf16((A), (B), (C), 0, 0, 0)

#define SEQ 2048
#define HD 128
#define NH 32
#define NKV 8

__device__ inline short f2bs(float f) {
    union { __hip_bfloat16 h; short s; } u;
    u.h = __float2bfloat16(f);
    return u.s;
}

__device__ inline short8_t load8(const __hip_bfloat16* p) {
    return *(const short8_t*)p;
}
__device__ inline short8_t load8(const float* p) {
    float4_t a = *(const float4_t*)p;
    float4_t b = *(const float4_t*)(p + 4);
    short8_t r;
    r[0] = f2bs(a[0]); r[1] = f2bs(a[1]); r[2] = f2bs(a[2]); r[3] = f2bs(a[3]);
    r[4] = f2bs(b[0]); r[5] = f2bs(b[1]); r[6] = f2bs(b[2]); r[7] = f2bs(b[3]);
    return r;
}

__device__ inline void store_c(__hip_bfloat16* p, float v) { *p = __float2bfloat16(v); }
__device__ inline void store_c(float* p, float v)          { *p = v; }

// ---------------------------------------------------------------------------
// C[m][n] = sum_k A[m][k] * B[n][k]  (row-major, K-contiguous; "NT")
// If TRC: store transposed per-batch: out[(b*N + n)*SEQ + s], b=m>>11, s=m&2047
// (used for the V projection so flash reads V^T directly).
// ---------------------------------------------------------------------------
template <typename TA, typename TB, typename TC, bool TRC = false>
__global__ __launch_bounds__(256) void gemm_bt(
    const TA* __restrict__ A,
    const TB* __restrict__ B,
    TC* __restrict__ C,
    int M, int N, int K)
{
    __shared__ short As[128][40];
    __shared__ short Bs[128][40];

    const int tid  = threadIdx.x;
    const int wave = tid >> 6;
    const int lane = tid & 63;
    const int quad = lane >> 4;
    const int l16  = lane & 15;
    const int m0 = blockIdx.y * 128;
    const int n0 = blockIdx.x * 128;
    const int wm = (wave >> 1) * 64;
    const int wn = (wave & 1) * 64;

    const int srow = tid >> 2;
    const int sseg = (tid & 3) * 8;

    float4_t acc[4][4] = {};

    for (int k0 = 0; k0 < K; k0 += 32) {
        short8_t a1 = load8(A + (size_t)(m0 + srow)      * K + k0 + sseg);
        short8_t a2 = load8(A + (size_t)(m0 + srow + 64) * K + k0 + sseg);
        short8_t b1 = load8(B + (size_t)(n0 + srow)      * K + k0 + sseg);
        short8_t b2 = load8(B + (size_t)(n0 + srow + 64) * K + k0 + sseg);
        __syncthreads();
        *(short8_t*)&As[srow][sseg]      = a1;
        *(short8_t*)&As[srow + 64][sseg] = a2;
        *(short8_t*)&Bs[srow][sseg]      = b1;
        *(short8_t*)&Bs[srow + 64][sseg] = b2;
        __syncthreads();

        short8_t af[4], bf[4];
#pragma unroll
        for (int t = 0; t < 4; t++)
            af[t] = *(const short8_t*)&As[wm + t * 16 + l16][quad * 8];
#pragma unroll
        for (int t = 0; t < 4; t++)
            bf[t] = *(const short8_t*)&Bs[wn + t * 16 + l16][quad * 8];
#pragma unroll
        for (int mt = 0; mt < 4; mt++)
#pragma unroll
            for (int nt = 0; nt < 4; nt++)
                acc[mt][nt] = MFMA16(af[mt], bf[nt], acc[mt][nt]);
    }

#pragma unroll
    for (int mt = 0; mt < 4; mt++)
#pragma unroll
        for (int nt = 0; nt < 4; nt++)
#pragma unroll
            for (int r = 0; r < 4; r++) {
                int row = m0 + wm + mt * 16 + quad * 4 + r;
                int col = n0 + wn + nt * 16 + l16;
                if constexpr (TRC) {
                    int bb = row >> 11, ss = row & (SEQ - 1);
                    C[((size_t)bb * N + col) * SEQ + ss] = __float2bfloat16(acc[mt][nt][r]);
                } else {
                    store_c(&C[(size_t)row * N + col], acc[mt][nt][r]);
                }
            }
}

// ---------------------------------------------------------------------------
// RoPE in-place; freqs fp32 [SEQ][64].
// ---------------------------------------------------------------------------
__global__ __launch_bounds__(256) void rope_kernel(
    __hip_bfloat16* __restrict__ x,
    const float* __restrict__ cs,
    const float* __restrict__ sn,
    int npairs, int shift)
{
    int pi = blockIdx.x * 256 + threadIdx.x;
    if (pi >= npairs) return;
    int cols = 1 << shift;
    int cp   = pi & (cols - 1);
    int row  = pi >> shift;
    int d    = cp & 63;
    int pos  = row & (SEQ - 1);
    float c = cs[pos * 64 + d];
    float s = sn[pos * 64 + d];
    __hip_bfloat16* p = x + (((size_t)row) << (shift + 1)) + (size_t)cp * 2;
    float x0 = __bfloat162float(p[0]);
    float x1 = __bfloat162float(p[1]);
    p[0] = __float2bfloat16(x0 * c - x1 * s);
    p[1] = __float2bfloat16(x0 * s + x1 * c);
}

// ---------------------------------------------------------------------------
// Causal GQA flash attention, swapped-operand layout.
// Grid: (S/64, NH, B), block 256 = 4 waves; wave w owns q rows w*16..+15.
// S^T = K*Q^T (key in regs, q in lanes) -> per-lane softmax (2 shuffles)
// -> P B-frags via ds_bpermute -> O^T += V^T * P^T with V^T staged directly
// from pre-transposed global VT. Epilogue transposes O^T via LDS (Ks reuse).
// ---------------------------------------------------------------------------
__global__ __launch_bounds__(256) void flash_kernel(
    const __hip_bfloat16* __restrict__ Q,
    const __hip_bfloat16* __restrict__ Km,
    const __hip_bfloat16* __restrict__ VT,
    __hip_bfloat16* __restrict__ O)
{
    __shared__ __hip_bfloat16 Ks[64][136];   // 272B row = 17 superbanks (good)
    __shared__ __hip_bfloat16 Vt[128][72];   // V^T tile: [d][key]

    const int tid  = threadIdx.x;
    const int wave = tid >> 6;
    const int lane = tid & 63;
    const int quad = lane >> 4;
    const int l16  = lane & 15;
    const int qt = (int)gridDim.x - 1 - (int)blockIdx.x;  // heavy blocks first
    const int h  = blockIdx.y;
    const int b  = blockIdx.z;
    const int kvh = h >> 2;
    const int q0  = qt * 64;
    const float scale = 0.08838834764831845f;  // 1/sqrt(128)
    const int qrow = q0 + wave * 16 + l16;     // this lane's q row

    // Q B-fragments straight from global (16 rows x 64B contiguous per load)
    short8_t qf[4];
    {
        const __hip_bfloat16* qp = Q + (size_t)(b * SEQ + qrow) * (NH * HD) + h * HD + quad * 8;
#pragma unroll
        for (int kk = 0; kk < 4; kk++)
            qf[kk] = *(const short8_t*)(qp + kk * 32);
    }

    float4_t acc[8] = {};          // O^T: acc[dm], d = dm*16 + quad*4 + r, q = l16
    float m_st = -1e30f, l_st = 0.f;

    const __hip_bfloat16* vbase = VT + ((size_t)(b * NKV + kvh) * HD) * SEQ;

    for (int kt = 0; kt <= qt; kt++) {
        __syncthreads();
        {
            const int seg = (tid & 15) * 8;
            const int row = tid >> 4;
#pragma unroll
            for (int i = 0; i < 4; i++) {
                int r = row + i * 16;
                *(uint4*)&Ks[r][seg] =
                    *(const uint4*)(Km + (size_t)(b * SEQ + kt * 64 + r) * (NKV * HD) + kvh * HD + seg);
            }
#pragma unroll
            for (int t = 0; t < 4; t++) {
                int c = tid + t * 256;
                int d = c >> 3, sl = (c & 7) * 8;
                *(uint4*)&Vt[d][sl] = *(const uint4*)(vbase + (size_t)d * SEQ + kt * 64 + sl);
            }
        }
        __syncthreads();

        // S^T[key][q]
        float4_t st[4] = {};
#pragma unroll
        for (int kk = 0; kk < 4; kk++)
#pragma unroll
            for (int mt = 0; mt < 4; mt++) {
                short8_t kf = *(const short8_t*)&Ks[mt * 16 + l16][kk * 32 + quad * 8];
                st[mt] = MFMA16(kf, qf[kk], st[mt]);
            }

        // per-lane softmax over this lane's 16 keys, then reduce across quads
        float mx = -1e30f;
#pragma unroll
        for (int mt = 0; mt < 4; mt++)
#pragma unroll
            for (int r = 0; r < 4; r++) {
                int key = kt * 64 + mt * 16 + quad * 4 + r;
                float s = st[mt][r] * scale;
                if (key > qrow) s = -1e30f;
                st[mt][r] = s;
                mx = fmaxf(mx, s);
            }
        mx = fmaxf(mx, __shfl_xor(mx, 16, 64));
        mx = fmaxf(mx, __shfl_xor(mx, 32, 64));
        float mnew  = fmaxf(m_st, mx);
        float alpha = __expf(m_st - mnew);
        float p[4][4];
        float rsum = 0.f;
#pragma unroll
        for (int mt = 0; mt < 4; mt++)
#pragma unroll
            for (int r = 0; r < 4; r++) {
                float pv = __expf(st[mt][r] - mnew);
                p[mt][r] = pv;
                rsum += pv;
            }
        rsum += __shfl_xor(rsum, 16, 64);
        rsum += __shfl_xor(rsum, 32, 64);
        l_st = l_st * alpha + rsum;
        m_st = mnew;
#pragma unroll
        for (int dm = 0; dm < 8; dm++)
            acc[dm] *= alpha;

        // pack P pairs: pk[mt][h] = keys (kt*64 + mt*16 + quad*4 + 2h, +2h+1)
        uint32_t pk[4][2];
#pragma unroll
        for (int mt = 0; mt < 4; mt++)
#pragma unroll
            for (int hh = 0; hh < 2; hh++)
                pk[mt][hh] = (uint32_t)(unsigned short)f2bs(p[mt][2 * hh]) |
                             ((uint32_t)(unsigned short)f2bs(p[mt][2 * hh + 1]) << 16);

        // build P^T B-fragments via cross-lane permutes
        const int src0 = ((quad & 1) * 2) * 16 + l16;
        const int src1 = src0 + 16;
        const bool hi_mt = (quad >> 1) != 0;
#pragma unroll
        for (int kk2 = 0; kk2 < 2; kk2++) {
            uint32_t a0 = (uint32_t)__shfl((int)pk[kk2 * 2][0],     src0, 64);
            uint32_t a1 = (uint32_t)__shfl((int)pk[kk2 * 2][1],     src0, 64);
            uint32_t a2 = (uint32_t)__shfl((int)pk[kk2 * 2][0],     src1, 64);
            uint32_t a3 = (uint32_t)__shfl((int)pk[kk2 * 2][1],     src1, 64);
            uint32_t b0 = (uint32_t)__shfl((int)pk[kk2 * 2 + 1][0], src0, 64);
            uint32_t b1 = (uint32_t)__shfl((int)pk[kk2 * 2 + 1][1], src0, 64);
            uint32_t b2 = (uint32_t)__shfl((int)pk[kk2 * 2 + 1][0], src1, 64);
            uint32_t b3 = (uint32_t)__shfl((int)pk[kk2 * 2 + 1][1], src1, 64);
            union { uint32_t u[4]; short8_t v; } pf;
            pf.u[0] = hi_mt ? b0 : a0;
            pf.u[1] = hi_mt ? b1 : a1;
            pf.u[2] = hi_mt ? b2 : a2;
            pf.u[3] = hi_mt ? b3 : a3;
#pragma unroll
            for (int dm = 0; dm < 8; dm++) {
                short8_t vf = *(const short8_t*)&Vt[dm * 16 + l16][kk2 * 32 + quad * 8];
                acc[dm] = MFMA16(vf, pf.v, acc[dm]);
            }
        }
    }

    // epilogue: O^T -> O via LDS transpose (reuse Ks; stride 136)
    __syncthreads();   // all waves done reading Ks/Vt
    __hip_bfloat16* Ot = &Ks[0][0];
    float inv_l = 1.f / l_st;
#pragma unroll
    for (int dm = 0; dm < 8; dm++)
#pragma unroll
        for (int hh = 0; hh < 2; hh++) {
            uint32_t pv = (uint32_t)(unsigned short)f2bs(acc[dm][2 * hh] * inv_l) |
                          ((uint32_t)(unsigned short)f2bs(acc[dm][2 * hh + 1] * inv_l) << 16);
            *(uint32_t*)&Ot[(size_t)(wave * 16 + l16) * 136 + dm * 16 + quad * 4 + 2 * hh] = pv;
        }
    __syncthreads();
#pragma unroll
    for (int i = 0; i < 4; i++) {
        int c  = i * 64 + lane;
        int r2 = c >> 4, ch = c & 15;
        uint4 v = *(const uint4*)&Ot[(size_t)(wave * 16 + r2) * 136 + ch * 8];
        *(uint4*)(O + (size_t)(b * SEQ + q0 + wave * 16 + r2) * (NH * HD) + h * HD + ch * 8) = v;
    }
}

// ---------------------------------------------------------------------------
extern "C" void kernel_launch(void* const* d_in, const int* in_sizes, int n_in,
                              void* d_out, int out_size, void* d_ws, size_t ws_size,
                              hipStream_t stream)
{
    const float* x  = (const float*)d_in[0];
    const float* fc = (const float*)d_in[1];
    const float* fs = (const float*)d_in[2];
    const float* wq = (const float*)d_in[3];
    const float* wk = (const float*)d_in[4];
    const float* wv = (const float*)d_in[5];
    const float* wo = (const float*)d_in[6];
    float* out = (float*)d_out;

    const int BS = 2 * SEQ;  // 4096 rows
    char* ws = (char*)d_ws;
    __hip_bfloat16* q    = (__hip_bfloat16*)(ws);                      // 4096x4096 bf16
    __hip_bfloat16* k    = (__hip_bfloat16*)(ws + (size_t)33554432);   // 4096x1024 bf16
    __hip_bfloat16* vT   = (__hip_bfloat16*)(ws + (size_t)41943040);   // [b][kvh][d][2048]
    __hip_bfloat16* attn = (__hip_bfloat16*)(ws + (size_t)50331648);   // 4096x4096 bf16

    gemm_bt<float, float, __hip_bfloat16, false><<<dim3(32, 32), 256, 0, stream>>>(x, wq, q, BS, NH * HD, 4096);
    gemm_bt<float, float, __hip_bfloat16, false><<<dim3(8, 32),  256, 0, stream>>>(x, wk, k, BS, NKV * HD, 4096);
    gemm_bt<float, float, __hip_bfloat16, true ><<<dim3(8, 32),  256, 0, stream>>>(x, wv, vT, BS, NKV * HD, 4096);

    {
        int npq = BS * NH * 64;
        rope_kernel<<<(npq + 255) / 256, 256, 0, stream>>>(q, fc, fs, npq, 11);
        int npk = BS * NKV * 64;
        rope_kernel<<<(npk + 255) / 256, 256, 0, stream>>>(k, fc, fs, npk, 9);
    }

    flash_kernel<<<dim3(SEQ / 64, NH, 2), 256, 0, stream>>>(q, k, vT, attn);

    gemm_bt<__hip_bfloat16, float, float, false><<<dim3(32, 32), 256, 0, stream>>>(attn, wo, out, BS, NH * HD, 4096);
}